// Round 7
// baseline (135.388 us; speedup 1.0000x reference)
//
#include <hip/hip_runtime.h>

#define DD 128
#define TILES 4          // 16-row MFMA tiles per wave -> 64 contiguous rows/wave

typedef __bf16 bf16x8 __attribute__((ext_vector_type(8)));
typedef float  f32x4  __attribute__((ext_vector_type(4)));

// Gather W[t] (fp32 [128][128] row-major) directly into per-lane MFMA
// B-fragments: wf[nt][kk] lane(q,n16) = w[kk*32+q*8+j][nt*16+n16], j=0..7.
// Per (nt,kk,j) inst: 16 lanes (n16) read 64B contiguous, 4 segments/wave.
// 256 dword loads total, one-time per wave (w is 1MB -> L2-resident).
__device__ __forceinline__ void gather_W(const float* __restrict__ wt,
                                         int q, int n16,
                                         bf16x8 wf[8][4]) {
    #pragma unroll
    for (int nt = 0; nt < 8; ++nt) {
        #pragma unroll
        for (int kk = 0; kk < 4; ++kk) {
            const float* p = wt + (kk * 32 + q * 8) * DD + nt * 16 + n16;
            bf16x8 v;
            #pragma unroll
            for (int j = 0; j < 8; ++j) v[j] = (__bf16)p[j * DD];
            wf[nt][kk] = v;
        }
    }
}

// ---------- 1-wave blocks, register-resident W, zero LDS, zero barriers ----------
// 2048 blocks x 64 threads; launch_bounds(64,2) -> 8 waves/CU, all co-resident.
// Each wave: gather W once (~256 L2 loads) then stream 4 tiles of 16 rows:
// 8 x-loads -> pack -> 32 reg-only MFMA -> 32 masked stores. Waves fully
// decoupled -> no phase-locking, loads/stores self-interleave across waves.
__global__ __launch_bounds__(64, 2) void hetero_reg_kernel(
    const float* __restrict__ x,
    const int*   __restrict__ tv,
    const float* __restrict__ w,      // [T][128][128] fp32
    const float* __restrict__ bias,   // [T][128]
    float*       __restrict__ out)    // [N][128]
{
    const int lane = threadIdx.x;
    const int q    = lane >> 4;
    const int n16  = lane & 15;
    const int row_base = blockIdx.x * (16 * TILES);

    // ---- x tile 0 prefetch FIRST: flies under tv load + W gather ----
    f32x4 xlo[4], xhi[4];
    {
        const float* b0 = x + (size_t)(row_base + n16) * DD + q * 8;
        #pragma unroll
        for (int kk = 0; kk < 4; ++kk) {
            xlo[kk] = *(const f32x4*)(b0 + kk * 32);
            xhi[kk] = *(const f32x4*)(b0 + kk * 32 + 4);
        }
    }

    int t_res = tv[row_base];

    bf16x8 wf[8][4];                 // 128 VGPRs: the whole B operand
    gather_W(w + (size_t)t_res * DD * DD, q, n16, wf);

    float bv[8];
    #pragma unroll
    for (int nt = 0; nt < 8; ++nt) bv[nt] = bias[t_res * DD + nt * 16 + n16];

    #pragma unroll
    for (int tile = 0; tile < TILES; ++tile) {
        const int row0 = row_base + tile * 16;

        // pack A fragments from the in-flight prefetch: A[m=n16][k=kk*32+q*8+j]
        bf16x8 a[4];
        #pragma unroll
        for (int kk = 0; kk < 4; ++kk) {
            bf16x8 t;
            t[0] = (__bf16)xlo[kk][0]; t[1] = (__bf16)xlo[kk][1];
            t[2] = (__bf16)xlo[kk][2]; t[3] = (__bf16)xlo[kk][3];
            t[4] = (__bf16)xhi[kk][0]; t[5] = (__bf16)xhi[kk][1];
            t[6] = (__bf16)xhi[kk][2]; t[7] = (__bf16)xhi[kk][3];
            a[kk] = t;
        }

        // reuse xlo/xhi for the next tile's prefetch (issued before stores,
        // so the next pack's vmcnt wait retires only these loads, not stores)
        if (tile + 1 < TILES) {
            const float* bn = x + (size_t)(row0 + 16 + n16) * DD + q * 8;
            #pragma unroll
            for (int kk = 0; kk < 4; ++kk) {
                xlo[kk] = *(const f32x4*)(bn + kk * 32);
                xhi[kk] = *(const f32x4*)(bn + kk * 32 + 4);
            }
        }

        const int tlo = tv[row0];
        const int thi = tv[row0 + 15];

        for (int t = tlo; t <= thi; ++t) {
            if (t != t_res) {               // rare: wave-uniform (<=15 waves grid-wide)
                gather_W(w + (size_t)t * DD * DD, q, n16, wf);
                #pragma unroll
                for (int nt = 0; nt < 8; ++nt) bv[nt] = bias[t * DD + nt * 16 + n16];
                t_res = t;
            }

            f32x4 acc[8];
            #pragma unroll
            for (int nt = 0; nt < 8; ++nt) acc[nt] = (f32x4){0.f, 0.f, 0.f, 0.f};

            #pragma unroll
            for (int nt = 0; nt < 8; ++nt) {
                #pragma unroll
                for (int kk = 0; kk < 4; ++kk)
                    acc[nt] = __builtin_amdgcn_mfma_f32_16x16x32_bf16(
                        a[kk], wf[nt][kk], acc[nt], 0, 0, 0);
            }

            // epilogue: D[row=q*4+reg][col=nt*16+n16]; 4x64B segments/store inst
            const int rbase = row0 + q * 4;
            bool m0 = true, m1 = true, m2 = true, m3 = true;
            if (tlo != thi) {
                m0 = (tv[rbase + 0] == t);
                m1 = (tv[rbase + 1] == t);
                m2 = (tv[rbase + 2] == t);
                m3 = (tv[rbase + 3] == t);
            }
            float* o = out + (size_t)rbase * DD + n16;
            #pragma unroll
            for (int nt = 0; nt < 8; ++nt) {
                float* oc = o + nt * 16;
                if (m0) oc[0 * DD] = acc[nt][0] + bv[nt];
                if (m1) oc[1 * DD] = acc[nt][1] + bv[nt];
                if (m2) oc[2 * DD] = acc[nt][2] + bv[nt];
                if (m3) oc[3 * DD] = acc[nt][3] + bv[nt];
            }
        }
    }
}

extern "C" void kernel_launch(void* const* d_in, const int* in_sizes, int n_in,
                              void* d_out, int out_size, void* d_ws, size_t ws_size,
                              hipStream_t stream) {
    const float* x    = (const float*)d_in[0];
    const int*   tv   = (const int*)d_in[1];
    const float* w    = (const float*)d_in[2];
    const float* bias = (const float*)d_in[3];
    float*       out  = (float*)d_out;

    int nrows = in_sizes[0] / DD;                  // 131072
    int grid  = nrows / (16 * TILES);              // 2048 one-wave blocks

    hipLaunchKernelGGL(hetero_reg_kernel, dim3(grid), dim3(64), 0, stream,
                       x, tv, w, bias, out);
}

// Round 8
// 124.637 us; speedup vs baseline: 1.0863x; 1.0863x over previous
//
#include <hip/hip_runtime.h>

#define DD 128
#define BM 64
#define CHUNK 4          // tiles per block -> 256 contiguous rows/block, grid 512 (2/CU, persistent)
#define T_TYPES 16

typedef __bf16 bf16x8 __attribute__((ext_vector_type(8)));
typedef float  f32x4  __attribute__((ext_vector_type(4)));

// async 16B global->LDS DMA: per-lane global addr, wave-uniform LDS base,
// HW scatters lane i at base + i*16.
__device__ __forceinline__ void async_copy16(const void* g, void* l) {
    __builtin_amdgcn_global_load_lds(
        (const __attribute__((address_space(1))) unsigned int*)g,
        (__attribute__((address_space(3))) unsigned int*)l, 16, 0, 0);
}

// ---------- Pre-kernel: w fp32 [t][k][n] -> bf16 MFMA-fragment order ----------
// wbf layout: [t][nt(8)][kk(4)][lane(64)][j(8)] bf16; B-fragment for (nt,kk)
// held by lane(q,n16) is B[k=kk*32+q*8+j][n=nt*16+n16] = w[t][k][n].
__global__ __launch_bounds__(256) void transpose_w_frag_kernel(
    const float* __restrict__ w, unsigned short* __restrict__ wbf)
{
    __shared__ float lds[DD * 33];
    const int t   = blockIdx.x >> 2;
    const int n0  = (blockIdx.x & 3) * 32;
    const int tid = threadIdx.x;
    const float* wt = w + (size_t)t * DD * DD;

    #pragma unroll
    for (int i = 0; i < 4; ++i) {
        int f = tid + i * 256;
        int k = f >> 3;
        int c = (f & 7) * 4;
        float4 v = *(const float4*)&wt[k * DD + n0 + c];
        lds[k * 33 + c + 0] = v.x;
        lds[k * 33 + c + 1] = v.y;
        lds[k * 33 + c + 2] = v.z;
        lds[k * 33 + c + 3] = v.w;
    }
    __syncthreads();
    #pragma unroll
    for (int i = 0; i < 4; ++i) {
        int g  = tid + i * 256;
        int nl = g >> 5;
        int k4 = (g & 31) * 4;
        int n  = n0 + nl;
        int nt  = n >> 4, n16 = n & 15;
        int kk  = k4 >> 5, q = (k4 >> 3) & 3, jb = k4 & 7;
        int lane = q * 16 + n16;
        size_t ofs = ((((size_t)t * 8 + nt) * 4 + kk) * 64 + lane) * 8 + jb;
        ushort4 o;
        union { __bf16 b; unsigned short u; } cv;
        cv.b = (__bf16)lds[(k4 + 0) * 33 + nl]; o.x = cv.u;
        cv.b = (__bf16)lds[(k4 + 1) * 33 + nl]; o.y = cv.u;
        cv.b = (__bf16)lds[(k4 + 2) * 33 + nl]; o.z = cv.u;
        cv.b = (__bf16)lds[(k4 + 3) * 33 + nl]; o.w = cv.u;
        *(ushort4*)&wbf[ofs] = o;
    }
}

// One tile: pack A from prefetch buffer, optionally re-fill the buffer with
// tile+2's rows (depth-2 pipeline), then the per-type MFMA + masked epilogue.
// Macro (not lambda) so all buffer indices stay compile-time -> registers.
#define PROCESS(XLO, XHI, TILE, PRE)                                          \
  do {                                                                        \
    const int trow0 = chunk0 + (TILE) * BM;                                   \
    const int wrow0 = trow0 + wave * 16;                                      \
    bf16x8 a[4];                                                              \
    _Pragma("unroll")                                                         \
    for (int kk = 0; kk < 4; ++kk) {                                          \
      bf16x8 t8;                                                              \
      t8[0] = (__bf16)XLO[kk][0]; t8[1] = (__bf16)XLO[kk][1];                 \
      t8[2] = (__bf16)XLO[kk][2]; t8[3] = (__bf16)XLO[kk][3];                 \
      t8[4] = (__bf16)XHI[kk][0]; t8[5] = (__bf16)XHI[kk][1];                 \
      t8[6] = (__bf16)XHI[kk][2]; t8[7] = (__bf16)XHI[kk][3];                 \
      a[kk] = t8;                                                             \
    }                                                                         \
    if (PRE) {  /* refill just-freed buffer with tile+2 (depth-2) */          \
      const float* bp = x + (size_t)(wrow0 + 2 * BM + n16) * DD + q * 8;      \
      _Pragma("unroll")                                                       \
      for (int kk = 0; kk < 4; ++kk) {                                        \
        XLO[kk] = *(const f32x4*)(bp + kk * 32);                              \
        XHI[kk] = *(const f32x4*)(bp + kk * 32 + 4);                          \
      }                                                                       \
    }                                                                         \
    const int tlo = tv[trow0];                                                \
    const int thi = tv[trow0 + BM - 1];                                       \
    for (int t = tlo; t <= thi; ++t) {                                        \
      if (t != t_res) {               /* rare: block-uniform branch */        \
        __syncthreads();              /* all waves done reading old Bs */     \
        const char* gsrc = (const char*)(wbf + (size_t)t * DD * DD);          \
        char* ldst = (char*)Bs;                                               \
        const int wofs = wave * 1024 + lane * 16;                             \
        _Pragma("unroll")                                                     \
        for (int r = 0; r < 8; ++r)                                           \
          async_copy16(gsrc + r * 4096 + wofs, ldst + r * 4096 + wave * 1024);\
        t_res = t;                                                            \
        _Pragma("unroll")                                                     \
        for (int nt = 0; nt < 8; ++nt) bv[nt] = bias[t * DD + nt * 16 + n16]; \
        __syncthreads();                                                      \
      }                                                                       \
      f32x4 acc[8];                                                           \
      _Pragma("unroll")                                                       \
      for (int nt = 0; nt < 8; ++nt) acc[nt] = (f32x4){0.f, 0.f, 0.f, 0.f};   \
      _Pragma("unroll")                                                       \
      for (int nt = 0; nt < 8; ++nt) {                                        \
        _Pragma("unroll")                                                     \
        for (int kk = 0; kk < 4; ++kk) {                                      \
          bf16x8 b = *(const bf16x8*)&Bs[(((nt << 2) | kk) << 9) | (lane << 3)];\
          acc[nt] = __builtin_amdgcn_mfma_f32_16x16x32_bf16(a[kk], b, acc[nt], 0, 0, 0);\
        }                                                                     \
      }                                                                       \
      const int rbase = wrow0 + q * 4;                                        \
      bool m0 = true, m1 = true, m2 = true, m3 = true;                        \
      if (tlo != thi) {                                                       \
        m0 = (tv[rbase + 0] == t);                                            \
        m1 = (tv[rbase + 1] == t);                                            \
        m2 = (tv[rbase + 2] == t);                                            \
        m3 = (tv[rbase + 3] == t);                                            \
      }                                                                       \
      float* o = out + (size_t)rbase * DD + n16;                              \
      _Pragma("unroll")                                                       \
      for (int nt = 0; nt < 8; ++nt) {                                        \
        float* oc = o + nt * 16;                                              \
        if (m0) oc[0 * DD] = acc[nt][0] + bv[nt];                             \
        if (m1) oc[1 * DD] = acc[nt][1] + bv[nt];                             \
        if (m2) oc[2 * DD] = acc[nt][2] + bv[nt];                             \
        if (m3) oc[3 * DD] = acc[nt][3] + bv[nt];                             \
      }                                                                       \
    }                                                                         \
  } while (0)

// ---------- Main kernel: persistent 2-blocks/CU, depth-2 x prefetch ----------
// A-fragments direct from global in MFMA layout; Bs-only LDS (32 KB).
// 512 blocks x 256 rows: long block lifetime -> one dispatch wave, no CP churn.
// (256,2): VGPR cap 256 gives room for two x-tiles in flight (depth-2 MLP).
__global__ __launch_bounds__(256, 2) void hetero_main_kernel(
    const float* __restrict__ x,
    const int*   __restrict__ tv,
    const __bf16* __restrict__ wbf,   // fragment-ordered bf16 W
    const float* __restrict__ bias,   // [T][128]
    float*       __restrict__ out)    // [N][128]
{
    __shared__ __bf16 Bs[DD * DD];       // 32 KB, fragment order

    const int tid  = threadIdx.x;
    const int wave = tid >> 6;
    const int lane = tid & 63;
    const int q    = lane >> 4;
    const int n16  = lane & 15;
    const int chunk0 = blockIdx.x * (BM * CHUNK);

    int t_res = tv[chunk0];

    // ---- W[t_res] -> Bs: 8 async DMA insts/wave, zero VGPR cost ----
    {
        const char* gsrc = (const char*)(wbf + (size_t)t_res * DD * DD);
        char* ldst = (char*)Bs;
        const int wofs = wave * 1024 + lane * 16;
        #pragma unroll
        for (int r = 0; r < 8; ++r)
            async_copy16(gsrc + r * 4096 + wofs, ldst + r * 4096 + wave * 1024);
    }

    // bias cached in regs for resident type
    float bv[8];
    #pragma unroll
    for (int nt = 0; nt < 8; ++nt) bv[nt] = bias[t_res * DD + nt * 16 + n16];

    // ---- prologue: tiles 0 and 1 both in flight (depth-2) ----
    f32x4 lo0[4], hi0[4], lo1[4], hi1[4];
    {
        const float* b0 = x + (size_t)(chunk0 + wave * 16 + n16) * DD + q * 8;
        const float* b1 = b0 + (size_t)BM * DD;
        #pragma unroll
        for (int kk = 0; kk < 4; ++kk) {
            lo0[kk] = *(const f32x4*)(b0 + kk * 32);
            hi0[kk] = *(const f32x4*)(b0 + kk * 32 + 4);
            lo1[kk] = *(const f32x4*)(b1 + kk * 32);
            hi1[kk] = *(const f32x4*)(b1 + kk * 32 + 4);
        }
    }

    __syncthreads();   // drain W DMA (all waves read all of Bs)

    PROCESS(lo0, hi0, 0, true);    // refills lo0/hi0 with tile 2
    PROCESS(lo1, hi1, 1, true);    // refills lo1/hi1 with tile 3
    PROCESS(lo0, hi0, 2, false);
    PROCESS(lo1, hi1, 3, false);
}

extern "C" void kernel_launch(void* const* d_in, const int* in_sizes, int n_in,
                              void* d_out, int out_size, void* d_ws, size_t ws_size,
                              hipStream_t stream) {
    const float* x    = (const float*)d_in[0];
    const int*   tv   = (const int*)d_in[1];
    const float* w    = (const float*)d_in[2];
    const float* bias = (const float*)d_in[3];
    float*       out  = (float*)d_out;
    unsigned short* wbf = (unsigned short*)d_ws;   // 512 KB

    int nrows = in_sizes[0] / DD;                  // 131072
    int grid  = nrows / (BM * CHUNK);              // 512

    hipLaunchKernelGGL(transpose_w_frag_kernel, dim3(T_TYPES * 4), dim3(256), 0, stream,
                       w, wbf);
    hipLaunchKernelGGL(hetero_main_kernel, dim3(grid), dim3(256), 0, stream,
                       x, tv, (const __bf16*)wbf, bias, out);
}

// Round 9
// 121.029 us; speedup vs baseline: 1.1186x; 1.0298x over previous
//
#include <hip/hip_runtime.h>

#define DD 128
#define BM 64
#define CHUNK 4          // tiles per block -> 256 contiguous rows/block, grid 512
#define T_TYPES 16

typedef __bf16 bf16x8 __attribute__((ext_vector_type(8)));
typedef __bf16 bf16x4 __attribute__((ext_vector_type(4)));
typedef float  f32x4  __attribute__((ext_vector_type(4)));

// async 16B global->LDS DMA: per-lane global addr, wave-uniform LDS base,
// HW scatters lane i at base + i*16.
__device__ __forceinline__ void async_copy16(const void* g, void* l) {
    __builtin_amdgcn_global_load_lds(
        (const __attribute__((address_space(1))) unsigned int*)g,
        (__attribute__((address_space(3))) unsigned int*)l, 16, 0, 0);
}

// ---------- Pre-kernel: w fp32 [t][k][n] -> bf16 MFMA-fragment order ----------
// wbf layout: [t][nt(8)][kk(4)][lane(64)][j(8)] bf16; B-fragment for (nt,kk)
// held by lane(q,n16) is B[k=kk*32+q*8+j][n=nt*16+n16] = w[t][k][n].
__global__ __launch_bounds__(256) void transpose_w_frag_kernel(
    const float* __restrict__ w, unsigned short* __restrict__ wbf)
{
    __shared__ float lds[DD * 33];
    const int t   = blockIdx.x >> 2;
    const int n0  = (blockIdx.x & 3) * 32;
    const int tid = threadIdx.x;
    const float* wt = w + (size_t)t * DD * DD;

    #pragma unroll
    for (int i = 0; i < 4; ++i) {
        int f = tid + i * 256;
        int k = f >> 3;
        int c = (f & 7) * 4;
        float4 v = *(const float4*)&wt[k * DD + n0 + c];
        lds[k * 33 + c + 0] = v.x;
        lds[k * 33 + c + 1] = v.y;
        lds[k * 33 + c + 2] = v.z;
        lds[k * 33 + c + 3] = v.w;
    }
    __syncthreads();
    #pragma unroll
    for (int i = 0; i < 4; ++i) {
        int g  = tid + i * 256;
        int nl = g >> 5;
        int k4 = (g & 31) * 4;
        int n  = n0 + nl;
        int nt  = n >> 4, n16 = n & 15;
        int kk  = k4 >> 5, q = (k4 >> 3) & 3, jb = k4 & 7;
        int lane = q * 16 + n16;
        size_t ofs = ((((size_t)t * 8 + nt) * 4 + kk) * 64 + lane) * 8 + jb;
        ushort4 o;
        union { __bf16 b; unsigned short u; } cv;
        cv.b = (__bf16)lds[(k4 + 0) * 33 + nl]; o.x = cv.u;
        cv.b = (__bf16)lds[(k4 + 1) * 33 + nl]; o.y = cv.u;
        cv.b = (__bf16)lds[(k4 + 2) * 33 + nl]; o.z = cv.u;
        cv.b = (__bf16)lds[(k4 + 3) * 33 + nl]; o.w = cv.u;
        *(ushort4*)&wbf[ofs] = o;
    }
}

// ---------- Main kernel: persistent 4-tile blocks, pipelined, barrier-free ----------
__global__ __launch_bounds__(256, 2) void hetero_main_kernel(
    const float* __restrict__ x,
    const int*   __restrict__ tv,
    const __bf16* __restrict__ wbf,   // fragment-ordered bf16 W
    const float* __restrict__ bias,   // [T][128]
    float*       __restrict__ out)    // [N][128]
{
    __shared__ __bf16 As[4 * 16 * DD];   // 4 per-wave private quadrants (16 KB)
    __shared__ __bf16 Bs[DD * DD];       // 32 KB, fragment order

    const int tid  = threadIdx.x;
    const int wave = tid >> 6;
    const int lane = tid & 63;
    const int q    = lane >> 4;
    const int n16  = lane & 15;
    const int chunk0 = blockIdx.x * (BM * CHUNK);

    __bf16* Aq = &As[wave * 16 * DD];

    int t_res = tv[chunk0];

    // ---- W[t_res] -> Bs: 8 async DMA insts/wave, zero VGPR cost ----
    {
        const char* gsrc = (const char*)(wbf + (size_t)t_res * DD * DD);
        char* ldst = (char*)Bs;
        const int wofs = wave * 1024 + lane * 16;
        #pragma unroll
        for (int r = 0; r < 8; ++r)
            async_copy16(gsrc + r * 4096 + wofs, ldst + r * 4096 + wave * 1024);
    }

    // bias cached in regs for resident type
    float bv[8];
    #pragma unroll
    for (int nt = 0; nt < 8; ++nt) bv[nt] = bias[t_res * DD + nt * 16 + n16];

    // ---- prefetch x tile 0 (wave's own 16 rows, perfectly coalesced) ----
    float4 xf[8];
    {
        const float4* p = (const float4*)(x + (size_t)(chunk0 + wave * 16) * DD);
        #pragma unroll
        for (int j = 0; j < 8; ++j) xf[j] = p[lane + 64 * j];
    }

    __syncthreads();   // drain W DMA (all waves read all of Bs)

    #pragma unroll
    for (int tile = 0; tile < CHUNK; ++tile) {
        const int trow0 = chunk0 + tile * BM;
        const int wrow0 = trow0 + wave * 16;

        // issue next tile's prefetch first -> loads fly under this tile's compute
        float4 xn[8];
        if (tile + 1 < CHUNK) {
            const float4* p = (const float4*)(x + (size_t)(wrow0 + BM) * DD);
            #pragma unroll
            for (int j = 0; j < 8; ++j) xn[j] = p[lane + 64 * j];
        }

        // stage current tile into this wave's LDS quadrant (swizzled granules).
        // Same-wave DS ordering => no barrier needed anywhere on the A path.
        #pragma unroll
        for (int j = 0; j < 8; ++j) {
            int f  = lane + 64 * j;
            int r  = f >> 5;
            int c4 = (f & 31) << 2;
            int g  = c4 >> 3;
            bf16x4 pk;
            pk[0] = (__bf16)xf[j].x; pk[1] = (__bf16)xf[j].y;
            pk[2] = (__bf16)xf[j].z; pk[3] = (__bf16)xf[j].w;
            *(bf16x4*)&Aq[r * DD + (((g ^ (r & 7)) << 3) | (c4 & 7))] = pk;
        }

        // A fragments: A[m=n16][k=kk*32+q*8+j], swizzle-corrected
        bf16x8 a[4];
        #pragma unroll
        for (int kk = 0; kk < 4; ++kk) {
            int gr = ((kk << 2) | q) ^ (n16 & 7);
            a[kk] = *(const bf16x8*)&Aq[n16 * DD + (gr << 3)];
        }

        const int tlo = tv[trow0];
        const int thi = tv[trow0 + BM - 1];

        for (int t = tlo; t <= thi; ++t) {
            if (t != t_res) {               // rare: block-uniform branch
                __syncthreads();            // all waves done reading old Bs
                const char* gsrc = (const char*)(wbf + (size_t)t * DD * DD);
                char* ldst = (char*)Bs;
                const int wofs = wave * 1024 + lane * 16;
                #pragma unroll
                for (int r = 0; r < 8; ++r)
                    async_copy16(gsrc + r * 4096 + wofs, ldst + r * 4096 + wave * 1024);
                t_res = t;
                #pragma unroll
                for (int nt = 0; nt < 8; ++nt) bv[nt] = bias[t * DD + nt * 16 + n16];
                __syncthreads();
            }

            f32x4 acc[8];
            #pragma unroll
            for (int nt = 0; nt < 8; ++nt) acc[nt] = (f32x4){0.f, 0.f, 0.f, 0.f};

            #pragma unroll
            for (int nt = 0; nt < 8; ++nt) {
                #pragma unroll
                for (int kk = 0; kk < 4; ++kk) {
                    bf16x8 b = *(const bf16x8*)&Bs[(((nt << 2) | kk) << 9) | (lane << 3)];
                    acc[nt] = __builtin_amdgcn_mfma_f32_16x16x32_bf16(a[kk], b, acc[nt], 0, 0, 0);
                }
            }

            // epilogue: D[row=q*4+reg][col=nt*16+n16]; 4x64B segments per store
            const int rbase = wrow0 + q * 4;
            bool m0 = true, m1 = true, m2 = true, m3 = true;
            if (tlo != thi) {
                m0 = (tv[rbase + 0] == t);
                m1 = (tv[rbase + 1] == t);
                m2 = (tv[rbase + 2] == t);
                m3 = (tv[rbase + 3] == t);
            }
            float* o = out + (size_t)rbase * DD + n16;
            #pragma unroll
            for (int nt = 0; nt < 8; ++nt) {
                float* oc = o + nt * 16;
                if (m0) oc[0 * DD] = acc[nt][0] + bv[nt];
                if (m1) oc[1 * DD] = acc[nt][1] + bv[nt];
                if (m2) oc[2 * DD] = acc[nt][2] + bv[nt];
                if (m3) oc[3 * DD] = acc[nt][3] + bv[nt];
            }
        }

        // hand prefetch buffer over
        #pragma unroll
        for (int j = 0; j < 8; ++j) xf[j] = xn[j];
    }
}

extern "C" void kernel_launch(void* const* d_in, const int* in_sizes, int n_in,
                              void* d_out, int out_size, void* d_ws, size_t ws_size,
                              hipStream_t stream) {
    const float* x    = (const float*)d_in[0];
    const int*   tv   = (const int*)d_in[1];
    const float* w    = (const float*)d_in[2];
    const float* bias = (const float*)d_in[3];
    float*       out  = (float*)d_out;
    unsigned short* wbf = (unsigned short*)d_ws;   // 512 KB

    int nrows = in_sizes[0] / DD;                  // 131072
    int grid  = nrows / (BM * CHUNK);              // 512

    hipLaunchKernelGGL(transpose_w_frag_kernel, dim3(T_TYPES * 4), dim3(256), 0, stream,
                       w, wbf);
    hipLaunchKernelGGL(hetero_main_kernel, dim3(grid), dim3(256), 0, stream,
                       x, tv, (const __bf16*)wbf, bias, out);
}